// Round 13
// baseline (100.231 us; speedup 1.0000x reference)
//
#include <hip/hip_runtime.h>
#include <stdint.h>

typedef int v4i  __attribute__((ext_vector_type(4)));
typedef int v16i __attribute__((ext_vector_type(16)));

// direct global->LDS DMA, 16B per lane (used by layer-2 kernel only)
__device__ __forceinline__ void gload_lds16(const void* g, void* l) {
    __builtin_amdgcn_global_load_lds(
        (const __attribute__((address_space(1))) void*)g,
        (__attribute__((address_space(3))) void*)l, 16, 0, 0);
}

// compiler-opaque 16B global load: no auto s_waitcnt on the result;
// completion enforced ONLY by counted vmcnt + sched_barrier fences.
__device__ __forceinline__ v4i gload16(const int8_t* p) {
    v4i r;
    asm volatile("global_load_dwordx4 %0, %1, off" : "=v"(r) : "v"(p) : "memory");
    return r;
}

// ================= packing: fragment layout [dimblk][kc][lane][16B] =========
// lane = (dim&31) + 32*khalf, byte = k&15. Values +1/-1 i8.
template<typename T, bool ISFLOAT>
__global__ __launch_bounds__(512)
void pack_frag(const T* __restrict__ in, int8_t* __restrict__ F, int K) {
    __shared__ int8_t lbuf[32 * 1040];
    const int t  = threadIdx.x;
    const int db = blockIdx.y;                  // dim block (32 rows)
    const int c0 = blockIdx.x << 10;            // k strip (1024 cols)

    #pragma unroll
    for (int p = 0; p < 16; ++p) {
        int idx = p * 512 + t;
        int row = idx >> 8, c4 = idx & 255;
        uint32_t b;
        if constexpr (ISFLOAT) {
            const float4 v = *(const float4*)(in + (size_t)(db * 32 + row) * K + c0 + c4 * 4);
            b =  (v.x >= 0.0f ? 0x01u : 0xFFu)
              | ((v.y >= 0.0f ? 0x01u : 0xFFu) << 8)
              | ((v.z >= 0.0f ? 0x01u : 0xFFu) << 16)
              | ((v.w >= 0.0f ? 0x01u : 0xFFu) << 24);
        } else {
            const int4 v = *(const int4*)(in + (size_t)(db * 32 + row) * K + c0 + c4 * 4);
            b =  (v.x ? 0x01u : 0xFFu)
              | ((v.y ? 0x01u : 0xFFu) << 8)
              | ((v.z ? 0x01u : 0xFFu) << 16)
              | ((v.w ? 0x01u : 0xFFu) << 24);
        }
        *(uint32_t*)(lbuf + row * 1040 + c4 * 4) = b;
    }
    __syncthreads();

    const int s  = t >> 4;                      // slab 0..31 (kc within strip)
    const int l0 = (t & 15) * 4;
    const int KC = K >> 5;
    int8_t* dst = F + ((size_t)db * KC + blockIdx.x * 32 + s) * 1024;
    #pragma unroll
    for (int li = 0; li < 4; ++li) {
        int l = l0 + li;
        uint4 v = *(const uint4*)(lbuf + (l & 31) * 1040 + s * 32 + (l >> 5) * 16);
        *(uint4*)(dst + l * 16) = v;
    }
}

// ================= layer 1: pure-register dataflow, NO LDS / NO barriers ====
// Tile 128x128, 256 thr = 4 waves (2 wr x 2 wc), wave-tile 64x64, acc[2][2].
// A and B both per-wave global->VGPR via opaque asm loads, 4-bank rings,
// prefetch distance 3, one counted vmcnt(16) per kt. Waves fully independent:
// 8 free-running streams/CU; serial chain per kt = vmcnt + 8 MFMA.
__global__ __launch_bounds__(256, 2)
void bnn_l1_flow(const int8_t* __restrict__ Af,   // [64][128][64][16]
                 const int8_t* __restrict__ Bf,   // [128][128][64][16]
                 const int* __restrict__ thr_ptr,
                 int8_t* __restrict__ actf)       // [64][128][64][16]
{
    constexpr int KC  = 128;
    constexpr int NKT = 64;

    __shared__ int8_t bits[128 * 144];          // epilogue transpose only (18KB)

    const int tid  = threadIdx.x;
    const int lane = tid & 63;
    const int wv   = tid >> 6;                  // 0..3
    const int wr   = wv >> 1, wc = wv & 1;

    // bijective XCD swizzle: 512 = 8 xcd-chunks x (4 bn x 16 bm)
    const int g   = blockIdx.x;
    const int idx = g >> 3;
    const int bn  = (g & 7) * 4 + (idx >> 4);   // 0..31
    const int bm  = idx & 15;                   // 0..15

    // per-wave operand bases; slabs: +0=(blk0,kc0) +1024=(blk0,kc1)
    // +131072=(blk1,kc0) +132096=(blk1,kc1); per-kt advance 2048B
    const int8_t* gA = Af + ((size_t)(bm * 4 + wr * 2) * KC) * 1024 + lane * 16;
    const int8_t* gB = Bf + ((size_t)(bn * 4 + wc * 2) * KC) * 1024 + lane * 16;

    v16i acc[2][2];
    #pragma unroll
    for (int i = 0; i < 2; ++i)
        #pragma unroll
        for (int j = 0; j < 2; ++j) acc[i][j] = {};

    v4i Ab[4][4], Bb[4][4];                     // [bank][slab], static idx only

    // prologue: banks 0..2 <- kt 0..2 (FIFO: 4 A then 4 B per kt)
    #pragma unroll
    for (int p = 0; p < 3; ++p) {
        const int8_t* ga = gA + p * 2048;
        Ab[p][0] = gload16(ga);
        Ab[p][1] = gload16(ga + 1024);
        Ab[p][2] = gload16(ga + 131072);
        Ab[p][3] = gload16(ga + 132096);
        const int8_t* gb = gB + p * 2048;
        Bb[p][0] = gload16(gb);
        Bb[p][1] = gload16(gb + 1024);
        Bb[p][2] = gload16(gb + 131072);
        Bb[p][3] = gload16(gb + 132096);
    }

#define KT_BODY(KT, P)                                                         \
    {                                                                          \
        const int kt_ = (KT);                                                  \
        if (kt_ < NKT - 2)       asm volatile("s_waitcnt vmcnt(16)" ::: "memory"); \
        else if (kt_ == NKT - 2) asm volatile("s_waitcnt vmcnt(8)"  ::: "memory"); \
        else                     asm volatile("s_waitcnt vmcnt(0)"  ::: "memory"); \
        __builtin_amdgcn_sched_barrier(0);                                     \
        if (kt_ + 3 < NKT) {                                                   \
            const int8_t* ga = gA + (kt_ + 3) * 2048;                          \
            Ab[((P)+3)&3][0] = gload16(ga);                                    \
            Ab[((P)+3)&3][1] = gload16(ga + 1024);                             \
            Ab[((P)+3)&3][2] = gload16(ga + 131072);                           \
            Ab[((P)+3)&3][3] = gload16(ga + 132096);                           \
            const int8_t* gb = gB + (kt_ + 3) * 2048;                          \
            Bb[((P)+3)&3][0] = gload16(gb);                                    \
            Bb[((P)+3)&3][1] = gload16(gb + 1024);                             \
            Bb[((P)+3)&3][2] = gload16(gb + 131072);                           \
            Bb[((P)+3)&3][3] = gload16(gb + 132096);                           \
        }                                                                      \
        __builtin_amdgcn_s_setprio(1);                                         \
        acc[0][0] = __builtin_amdgcn_mfma_i32_32x32x32_i8(Ab[P][0], Bb[P][0], acc[0][0], 0, 0, 0); \
        acc[0][1] = __builtin_amdgcn_mfma_i32_32x32x32_i8(Ab[P][0], Bb[P][2], acc[0][1], 0, 0, 0); \
        acc[1][0] = __builtin_amdgcn_mfma_i32_32x32x32_i8(Ab[P][2], Bb[P][0], acc[1][0], 0, 0, 0); \
        acc[1][1] = __builtin_amdgcn_mfma_i32_32x32x32_i8(Ab[P][2], Bb[P][2], acc[1][1], 0, 0, 0); \
        acc[0][0] = __builtin_amdgcn_mfma_i32_32x32x32_i8(Ab[P][1], Bb[P][1], acc[0][0], 0, 0, 0); \
        acc[0][1] = __builtin_amdgcn_mfma_i32_32x32x32_i8(Ab[P][1], Bb[P][3], acc[0][1], 0, 0, 0); \
        acc[1][0] = __builtin_amdgcn_mfma_i32_32x32x32_i8(Ab[P][3], Bb[P][1], acc[1][0], 0, 0, 0); \
        acc[1][1] = __builtin_amdgcn_mfma_i32_32x32x32_i8(Ab[P][3], Bb[P][3], acc[1][1], 0, 0, 0); \
        __builtin_amdgcn_s_setprio(0);                                         \
        __builtin_amdgcn_sched_barrier(0);                                     \
    }

    #pragma unroll 1
    for (int kt0 = 0; kt0 < NKT; kt0 += 4) {
        KT_BODY(kt0 + 0, 0)
        KT_BODY(kt0 + 1, 1)
        KT_BODY(kt0 + 2, 2)
        KT_BODY(kt0 + 3, 3)
    }
#undef KT_BODY

    // ---- epilogue: threshold -> +-1 bytes -> LDS transpose -> Act slabs ----
    __syncthreads();
    const int thr = *thr_ptr;
    #pragma unroll
    for (int i = 0; i < 2; ++i)
        #pragma unroll
        for (int j = 0; j < 2; ++j) {
            int dimb = wr * 64 + i * 32 + 4 * (lane >> 5);
            int gcl  = wc * 64 + j * 32 + (lane & 31);
            #pragma unroll
            for (int reg = 0; reg < 16; ++reg) {
                int dl = dimb + (reg & 3) + 8 * (reg >> 2);
                int match = (4096 + acc[i][j][reg]) >> 1;
                bits[dl * 144 + gcl] = (match >= thr) ? (int8_t)1 : (int8_t)-1;
            }
        }
    __syncthreads();
    // 16 slabs (4 dimblk x 4 kc) x 1KB; 16 threads/slab, 4 lanes each
    const int s    = tid >> 4;                  // 0..15
    const int dblk = s >> 2, kcl = s & 3;
    const int l0   = (tid & 15) * 4;
    int8_t* dst = actf + ((size_t)(bm * 4 + dblk) * KC + bn * 4 + kcl) * 1024;
    #pragma unroll
    for (int li = 0; li < 4; ++li) {
        int l = l0 + li;
        uint4 v = *(const uint4*)(bits + (dblk * 32 + (l & 31)) * 144
                                       + kcl * 32 + (l >> 5) * 16);
        *(uint4*)(dst + l * 16) = v;
    }
}

// ================= layer 2: round-9 proven kernel (128x64 tiles) ============
template<int WN>
__global__ __launch_bounds__(256, 1)
void bnn_mfma2(const int8_t* __restrict__ Af,
               const int8_t* __restrict__ Bf,
               int* __restrict__ out, int Nout)
{
    constexpr int KC     = 128;
    constexpr int NKT    = 64;
    constexpr int NBB    = 2 * WN;
    constexpr int ASLOTS = 512;
    constexpr int BSLOTS = 128 * NBB;
    constexpr int SLOTS  = ASLOTS + BSLOTS;
    constexpr int NLD    = SLOTS / 256;
    constexpr uint32_t BUFSZ = (uint32_t)SLOTS * 16;

    __shared__ int8_t lds[3][SLOTS * 16];

    const int tid  = threadIdx.x;
    const int lane = tid & 63;
    const int wv   = tid >> 6;
    const int wr   = wv >> 1, wc = wv & 1;

    const int g   = blockIdx.x;
    const int idx = g >> 3;
    const int bn  = (g & 7) * 2 + (idx >> 4);
    const int bm  = idx & 15;

    const int8_t* gsrc[NLD];
    uint32_t ldoff[NLD];
    #pragma unroll
    for (int i = 0; i < NLD; ++i) {
        int sbase = wv * 64 + 256 * i;
        ldoff[i] = (uint32_t)sbase * 16;
        const int8_t* base;
        if (sbase < ASLOTS) {
            int R = sbase >> 7, C = (sbase >> 6) & 1;
            base = Af + ((size_t)(bm * 4 + R) * KC + C) * 1024;
        } else {
            int s = sbase - ASLOTS;
            int R = s >> 7, C = (s >> 6) & 1;
            base = Bf + ((size_t)(bn * NBB + R) * KC + C) * 1024;
        }
        gsrc[i] = base + lane * 16;
    }

    auto stage = [&](int buf) {
        #pragma unroll
        for (int i = 0; i < NLD; ++i) {
            gload_lds16(gsrc[i], (int8_t*)lds + (uint32_t)buf * BUFSZ + ldoff[i]);
            gsrc[i] += 2048;
        }
    };

    v16i acc[2][WN];
    #pragma unroll
    for (int i = 0; i < 2; ++i)
        #pragma unroll
        for (int j = 0; j < WN; ++j) acc[i][j] = {};

    stage(0);
    stage(1);

    int cur = 0, nxt = 2;
    #pragma unroll 1
    for (int kt = 0; kt < NKT; ++kt) {
        if (kt < NKT - 1) asm volatile("s_waitcnt vmcnt(3)" ::: "memory");
        else              asm volatile("s_waitcnt vmcnt(0)" ::: "memory");
        __builtin_amdgcn_sched_barrier(0);
        __builtin_amdgcn_s_barrier();
        __builtin_amdgcn_sched_barrier(0);

        if (kt < NKT - 2) {
            stage(nxt);
            nxt = (nxt == 2) ? 0 : nxt + 1;
        }

        const int8_t* Al = lds[cur];
        const int8_t* Bl = lds[cur] + ASLOTS * 16;
        #pragma unroll
        for (int kc = 0; kc < 2; ++kc) {
            v4i af[2], bf[WN];
            #pragma unroll
            for (int i = 0; i < 2; ++i)
                af[i] = *(const v4i*)(Al + (((wr * 2 + i) * 2 + kc) * 64 + lane) * 16);
            #pragma unroll
            for (int j = 0; j < WN; ++j)
                bf[j] = *(const v4i*)(Bl + (((wc * WN + j) * 2 + kc) * 64 + lane) * 16);
            #pragma unroll
            for (int i = 0; i < 2; ++i)
                #pragma unroll
                for (int j = 0; j < WN; ++j)
                    acc[i][j] = __builtin_amdgcn_mfma_i32_32x32x32_i8(af[i], bf[j], acc[i][j], 0, 0, 0);
        }
        cur = (cur == 2) ? 0 : cur + 1;
    }

    #pragma unroll
    for (int i = 0; i < 2; ++i)
        #pragma unroll
        for (int j = 0; j < WN; ++j) {
            int gc = bn * (64 * WN) + wc * (32 * WN) + j * 32 + (lane & 31);
            #pragma unroll
            for (int reg = 0; reg < 16; ++reg) {
                int gr = bm * 128 + wr * 64 + i * 32
                       + (reg & 3) + 8 * (reg >> 2) + 4 * (lane >> 5);
                out[(size_t)gr * Nout + gc] = (4096 + acc[i][j][reg]) >> 1;
            }
        }
}

// ============================ launcher ============================
extern "C" void kernel_launch(void* const* d_in, const int* in_sizes, int n_in,
                              void* d_out, int out_size, void* d_ws, size_t ws_size,
                              hipStream_t stream) {
    const float* x   = (const float*)d_in[0];
    const int*   w1  = (const int*)d_in[1];
    const int*   w2  = (const int*)d_in[2];
    const int*   thr = (const int*)d_in[3];
    int* out = (int*)d_out;

    const int B = 2048, IN = 4096, H = 4096, OUT = 1024;
    uint8_t* ws = (uint8_t*)d_ws;

    // Af 8MB | W1f 16MB | W2f 4MB | Act 8MB
    int8_t* Af  = (int8_t*)(ws);
    int8_t* W1f = (int8_t*)(ws + ((size_t)8  << 20));
    int8_t* W2f = (int8_t*)(ws + ((size_t)24 << 20));
    int8_t* Act = (int8_t*)(ws + ((size_t)28 << 20));

    pack_frag<float, true ><<<dim3(IN / 1024, B   / 32), 512, 0, stream>>>(x,  Af,  IN);
    pack_frag<int,   false><<<dim3(IN / 1024, H   / 32), 512, 0, stream>>>(w1, W1f, IN);
    pack_frag<int,   false><<<dim3(H  / 1024, OUT / 32), 512, 0, stream>>>(w2, W2f, H);

    bnn_l1_flow<<<512, 256, 0, stream>>>(Af, W1f, thr, Act);                    // 128x128 tiles
    bnn_mfma2<1><<<256, 256, 0, stream>>>(Act, W2f, out, OUT);                  // 128x64 tiles
}

// Round 14
// 88.153 us; speedup vs baseline: 1.1370x; 1.1370x over previous
//
#include <hip/hip_runtime.h>
#include <stdint.h>

typedef int v4i  __attribute__((ext_vector_type(4)));
typedef int v16i __attribute__((ext_vector_type(16)));

// direct global->LDS DMA, 16B per lane; LDS dest is wave-uniform base + lane*16
__device__ __forceinline__ void gload_lds16(const void* g, void* l) {
    __builtin_amdgcn_global_load_lds(
        (const __attribute__((address_space(1))) void*)g,
        (__attribute__((address_space(3))) void*)l, 16, 0, 0);
}

// ================= packing: fragment layout [dimblk][kc][lane][16B] =========
// lane = (dim&31) + 32*khalf, byte = k&15. Values +1/-1 i8.
template<typename T, bool ISFLOAT>
__global__ __launch_bounds__(512)
void pack_frag(const T* __restrict__ in, int8_t* __restrict__ F, int K) {
    __shared__ int8_t lbuf[32 * 1040];
    const int t  = threadIdx.x;
    const int db = blockIdx.y;                  // dim block (32 rows)
    const int c0 = blockIdx.x << 10;            // k strip (1024 cols)

    #pragma unroll
    for (int p = 0; p < 16; ++p) {
        int idx = p * 512 + t;
        int row = idx >> 8, c4 = idx & 255;
        uint32_t b;
        if constexpr (ISFLOAT) {
            const float4 v = *(const float4*)(in + (size_t)(db * 32 + row) * K + c0 + c4 * 4);
            b =  (v.x >= 0.0f ? 0x01u : 0xFFu)
              | ((v.y >= 0.0f ? 0x01u : 0xFFu) << 8)
              | ((v.z >= 0.0f ? 0x01u : 0xFFu) << 16)
              | ((v.w >= 0.0f ? 0x01u : 0xFFu) << 24);
        } else {
            const int4 v = *(const int4*)(in + (size_t)(db * 32 + row) * K + c0 + c4 * 4);
            b =  (v.x ? 0x01u : 0xFFu)
              | ((v.y ? 0x01u : 0xFFu) << 8)
              | ((v.z ? 0x01u : 0xFFu) << 16)
              | ((v.w ? 0x01u : 0xFFu) << 24);
        }
        *(uint32_t*)(lbuf + row * 1040 + c4 * 4) = b;
    }
    __syncthreads();

    const int s  = t >> 4;                      // slab 0..31 (kc within strip)
    const int l0 = (t & 15) * 4;
    const int KC = K >> 5;
    int8_t* dst = F + ((size_t)db * KC + blockIdx.x * 32 + s) * 1024;
    #pragma unroll
    for (int li = 0; li < 4; ++li) {
        int l = l0 + li;
        uint4 v = *(const uint4*)(lbuf + (l & 31) * 1040 + s * 32 + (l >> 5) * 16);
        *(uint4*)(dst + l * 16) = v;
    }
}

// ================= layer 1: byte-optimal tiles + single-barrier pipeline ====
// Tile 128x256, 512 thr = 8 waves (2 wr x 4 wc), wave-tile 64x64, acc[2][2].
// ALL operands via gload_lds (24 KB/block-kt, zero duplication = TCP-optimal).
// 4-buffer LDS ring, prefetch distance 3, ONE s_barrier + counted vmcnt(6)/kt.
__global__ __launch_bounds__(512, 1)
void bnn_l1_opt(const int8_t* __restrict__ Af,   // [64][128][64][16]
                const int8_t* __restrict__ Bf,   // [128][128][64][16]
                const int* __restrict__ thr_ptr,
                int8_t* __restrict__ actf)       // [64][128][64][16]
{
    constexpr int KC  = 128;
    constexpr int NKT = 64;
    constexpr uint32_t BUFSZ = 24576;           // A 8KB (4 rowblk) + B 16KB (8 colblk)

    __shared__ int8_t lds[4 * 24576];           // 96KB ring; reused as bits (34.8KB)

    const int tid  = threadIdx.x;
    const int lane = tid & 63;
    const int wv   = tid >> 6;                  // 0..7
    const int wr   = wv >> 2, wc = wv & 3;

    // bijective XCD swizzle: grid 256 = 16(bn) x 16(bm)
    const int g   = blockIdx.x;
    const int idx = g >> 3;
    const int bn  = (g & 7) * 2 + (idx >> 4);
    const int bm  = idx & 15;

    // staging: 3 gload_lds/thread/kt; slot = c*512 + tid
    const int8_t* gsrc[3];
    uint32_t loff[3];
    #pragma unroll
    for (int c = 0; c < 3; ++c) {
        int s = c * 512 + tid;
        if (s < 512) {                          // A: rowblk, kc, lane
            int R = s >> 7, kk = (s >> 6) & 1, ln = s & 63;
            gsrc[c] = Af + ((size_t)(bm * 4 + R) * KC + kk) * 1024 + ln * 16;
            loff[c] = (uint32_t)s * 16;
        } else {                                // B: colblk, kc, lane
            int s2 = s - 512;
            int Cb = s2 >> 7, kk = (s2 >> 6) & 1, ln = s2 & 63;
            gsrc[c] = Bf + ((size_t)(bn * 8 + Cb) * KC + kk) * 1024 + ln * 16;
            loff[c] = 8192u + (uint32_t)s2 * 16;
        }
    }

    auto issue3 = [&](uint32_t bufo) {
        gload_lds16(gsrc[0], lds + bufo + loff[0]); gsrc[0] += 2048;
        gload_lds16(gsrc[1], lds + bufo + loff[1]); gsrc[1] += 2048;
        gload_lds16(gsrc[2], lds + bufo + loff[2]); gsrc[2] += 2048;
    };

    v16i acc[2][2];
    #pragma unroll
    for (int i = 0; i < 2; ++i)
        #pragma unroll
        for (int j = 0; j < 2; ++j) acc[i][j] = {};

    // prologue: kt 0,1,2 -> buf 0,1,2 (3 gloads/thread each; FIFO order)
    issue3(0);
    issue3(BUFSZ);
    issue3(2 * BUFSZ);

#define KT_BODY(KT, P)                                                         \
    {                                                                          \
        const int kt_ = (KT);                                                  \
        if (kt_ < NKT - 2)       asm volatile("s_waitcnt vmcnt(6)" ::: "memory"); \
        else if (kt_ == NKT - 2) asm volatile("s_waitcnt vmcnt(3)" ::: "memory"); \
        else                     asm volatile("s_waitcnt vmcnt(0)" ::: "memory"); \
        __builtin_amdgcn_sched_barrier(0);                                     \
        __builtin_amdgcn_s_barrier();                                          \
        __builtin_amdgcn_sched_barrier(0);                                     \
        const int8_t* Ab = lds + (P) * 24576 + wr * 4096 + lane * 16;          \
        const int8_t* Bb = lds + (P) * 24576 + 8192 + wc * 4096 + lane * 16;   \
        v4i a00 = *(const v4i*)(Ab + 0);                                       \
        v4i a01 = *(const v4i*)(Ab + 1024);                                    \
        v4i a10 = *(const v4i*)(Ab + 2048);                                    \
        v4i a11 = *(const v4i*)(Ab + 3072);                                    \
        v4i b00 = *(const v4i*)(Bb + 0);                                       \
        v4i b01 = *(const v4i*)(Bb + 1024);                                    \
        v4i b10 = *(const v4i*)(Bb + 2048);                                    \
        v4i b11 = *(const v4i*)(Bb + 3072);                                    \
        if (kt_ + 3 < NKT) issue3(((P) + 3) % 4 * 24576u);                     \
        __builtin_amdgcn_sched_barrier(0);                                     \
        asm volatile("s_waitcnt lgkmcnt(0)" ::: "memory");                     \
        __builtin_amdgcn_sched_barrier(0);                                     \
        __builtin_amdgcn_s_setprio(1);                                         \
        acc[0][0] = __builtin_amdgcn_mfma_i32_32x32x32_i8(a00, b00, acc[0][0], 0, 0, 0); \
        acc[0][1] = __builtin_amdgcn_mfma_i32_32x32x32_i8(a00, b10, acc[0][1], 0, 0, 0); \
        acc[1][0] = __builtin_amdgcn_mfma_i32_32x32x32_i8(a10, b00, acc[1][0], 0, 0, 0); \
        acc[1][1] = __builtin_amdgcn_mfma_i32_32x32x32_i8(a10, b10, acc[1][1], 0, 0, 0); \
        acc[0][0] = __builtin_amdgcn_mfma_i32_32x32x32_i8(a01, b01, acc[0][0], 0, 0, 0); \
        acc[0][1] = __builtin_amdgcn_mfma_i32_32x32x32_i8(a01, b11, acc[0][1], 0, 0, 0); \
        acc[1][0] = __builtin_amdgcn_mfma_i32_32x32x32_i8(a11, b01, acc[1][0], 0, 0, 0); \
        acc[1][1] = __builtin_amdgcn_mfma_i32_32x32x32_i8(a11, b11, acc[1][1], 0, 0, 0); \
        __builtin_amdgcn_s_setprio(0);                                         \
        __builtin_amdgcn_sched_barrier(0);                                     \
    }

    #pragma unroll 1
    for (int kt0 = 0; kt0 < NKT; kt0 += 4) {
        KT_BODY(kt0 + 0, 0)
        KT_BODY(kt0 + 1, 1)
        KT_BODY(kt0 + 2, 2)
        KT_BODY(kt0 + 3, 3)
    }
#undef KT_BODY

    // ---- epilogue: threshold -> +-1 bytes -> LDS transpose -> Act slabs ----
    __syncthreads();
    const int thr = *thr_ptr;
    int8_t* bits = lds;                         // [128][272] = 34.8KB
    #pragma unroll
    for (int i = 0; i < 2; ++i)
        #pragma unroll
        for (int j = 0; j < 2; ++j) {
            int dimb = wr * 64 + i * 32 + 4 * (lane >> 5);
            int gcl  = wc * 64 + j * 32 + (lane & 31);
            #pragma unroll
            for (int reg = 0; reg < 16; ++reg) {
                int dl = dimb + (reg & 3) + 8 * (reg >> 2);
                int match = (4096 + acc[i][j][reg]) >> 1;
                bits[dl * 272 + gcl] = (match >= thr) ? (int8_t)1 : (int8_t)-1;
            }
        }
    __syncthreads();
    // 32 slabs (4 dimblk x 8 kc) x 1KB; 16 threads/slab, 4 lanes each
    const int s    = tid >> 4;
    const int dblk = s >> 3, kcl = s & 7;
    const int l0   = (tid & 15) * 4;
    int8_t* dst = actf + ((size_t)(bm * 4 + dblk) * KC + bn * 8 + kcl) * 1024;
    #pragma unroll
    for (int li = 0; li < 4; ++li) {
        int l = l0 + li;
        uint4 v = *(const uint4*)(bits + (dblk * 32 + (l & 31)) * 272
                                       + kcl * 32 + (l >> 5) * 16);
        *(uint4*)(dst + l * 16) = v;
    }
}

// ================= layer 2: round-9 proven kernel (128x64 tiles) ============
template<int WN>
__global__ __launch_bounds__(256, 1)
void bnn_mfma2(const int8_t* __restrict__ Af,
               const int8_t* __restrict__ Bf,
               int* __restrict__ out, int Nout)
{
    constexpr int KC     = 128;
    constexpr int NKT    = 64;
    constexpr int NBB    = 2 * WN;
    constexpr int ASLOTS = 512;
    constexpr int BSLOTS = 128 * NBB;
    constexpr int SLOTS  = ASLOTS + BSLOTS;
    constexpr int NLD    = SLOTS / 256;
    constexpr uint32_t BUFSZ = (uint32_t)SLOTS * 16;

    __shared__ int8_t lds[3][SLOTS * 16];

    const int tid  = threadIdx.x;
    const int lane = tid & 63;
    const int wv   = tid >> 6;
    const int wr   = wv >> 1, wc = wv & 1;

    const int g   = blockIdx.x;
    const int idx = g >> 3;
    const int bn  = (g & 7) * 2 + (idx >> 4);
    const int bm  = idx & 15;

    const int8_t* gsrc[NLD];
    uint32_t ldoff[NLD];
    #pragma unroll
    for (int i = 0; i < NLD; ++i) {
        int sbase = wv * 64 + 256 * i;
        ldoff[i] = (uint32_t)sbase * 16;
        const int8_t* base;
        if (sbase < ASLOTS) {
            int R = sbase >> 7, C = (sbase >> 6) & 1;
            base = Af + ((size_t)(bm * 4 + R) * KC + C) * 1024;
        } else {
            int s = sbase - ASLOTS;
            int R = s >> 7, C = (s >> 6) & 1;
            base = Bf + ((size_t)(bn * NBB + R) * KC + C) * 1024;
        }
        gsrc[i] = base + lane * 16;
    }

    auto stage = [&](int buf) {
        #pragma unroll
        for (int i = 0; i < NLD; ++i) {
            gload_lds16(gsrc[i], (int8_t*)lds + (uint32_t)buf * BUFSZ + ldoff[i]);
            gsrc[i] += 2048;
        }
    };

    v16i acc[2][WN];
    #pragma unroll
    for (int i = 0; i < 2; ++i)
        #pragma unroll
        for (int j = 0; j < WN; ++j) acc[i][j] = {};

    stage(0);
    stage(1);

    int cur = 0, nxt = 2;
    #pragma unroll 1
    for (int kt = 0; kt < NKT; ++kt) {
        if (kt < NKT - 1) asm volatile("s_waitcnt vmcnt(3)" ::: "memory");
        else              asm volatile("s_waitcnt vmcnt(0)" ::: "memory");
        __builtin_amdgcn_sched_barrier(0);
        __builtin_amdgcn_s_barrier();
        __builtin_amdgcn_sched_barrier(0);

        if (kt < NKT - 2) {
            stage(nxt);
            nxt = (nxt == 2) ? 0 : nxt + 1;
        }

        const int8_t* Al = lds[cur];
        const int8_t* Bl = lds[cur] + ASLOTS * 16;
        #pragma unroll
        for (int kc = 0; kc < 2; ++kc) {
            v4i af[2], bf[WN];
            #pragma unroll
            for (int i = 0; i < 2; ++i)
                af[i] = *(const v4i*)(Al + (((wr * 2 + i) * 2 + kc) * 64 + lane) * 16);
            #pragma unroll
            for (int j = 0; j < WN; ++j)
                bf[j] = *(const v4i*)(Bl + (((wc * WN + j) * 2 + kc) * 64 + lane) * 16);
            #pragma unroll
            for (int i = 0; i < 2; ++i)
                #pragma unroll
                for (int j = 0; j < WN; ++j)
                    acc[i][j] = __builtin_amdgcn_mfma_i32_32x32x32_i8(af[i], bf[j], acc[i][j], 0, 0, 0);
        }
        cur = (cur == 2) ? 0 : cur + 1;
    }

    #pragma unroll
    for (int i = 0; i < 2; ++i)
        #pragma unroll
        for (int j = 0; j < WN; ++j) {
            int gc = bn * (64 * WN) + wc * (32 * WN) + j * 32 + (lane & 31);
            #pragma unroll
            for (int reg = 0; reg < 16; ++reg) {
                int gr = bm * 128 + wr * 64 + i * 32
                       + (reg & 3) + 8 * (reg >> 2) + 4 * (lane >> 5);
                out[(size_t)gr * Nout + gc] = (4096 + acc[i][j][reg]) >> 1;
            }
        }
}

// ============================ launcher ============================
extern "C" void kernel_launch(void* const* d_in, const int* in_sizes, int n_in,
                              void* d_out, int out_size, void* d_ws, size_t ws_size,
                              hipStream_t stream) {
    const float* x   = (const float*)d_in[0];
    const int*   w1  = (const int*)d_in[1];
    const int*   w2  = (const int*)d_in[2];
    const int*   thr = (const int*)d_in[3];
    int* out = (int*)d_out;

    const int B = 2048, IN = 4096, H = 4096, OUT = 1024;
    uint8_t* ws = (uint8_t*)d_ws;

    // Af 8MB | W1f 16MB | W2f 4MB | Act 8MB
    int8_t* Af  = (int8_t*)(ws);
    int8_t* W1f = (int8_t*)(ws + ((size_t)8  << 20));
    int8_t* W2f = (int8_t*)(ws + ((size_t)24 << 20));
    int8_t* Act = (int8_t*)(ws + ((size_t)28 << 20));

    pack_frag<float, true ><<<dim3(IN / 1024, B   / 32), 512, 0, stream>>>(x,  Af,  IN);
    pack_frag<int,   false><<<dim3(IN / 1024, H   / 32), 512, 0, stream>>>(w1, W1f, IN);
    pack_frag<int,   false><<<dim3(H  / 1024, OUT / 32), 512, 0, stream>>>(w2, W2f, H);

    bnn_l1_opt<<<256, 512, 0, stream>>>(Af, W1f, thr, Act);                     // 128x256 tiles
    bnn_mfma2<1><<<256, 256, 0, stream>>>(Act, W2f, out, OUT);                  // 128x64 tiles
}